// Round 10
// baseline (344.399 us; speedup 1.0000x reference)
//
#include <hip/hip_runtime.h>
#include <cstdio>
#include <math.h>

// ---------------------------------------------------------------------------
// MeshEncoderDecoder — round 10: mesh2 re-tiled to 256-thread / TILE_E=32
// blocks (16.9 KB LDS -> 8 blocks/CU, 2x independent barrier groups per CU).
// Everything else as round 9.
// ---------------------------------------------------------------------------

#define E_TOT 50000
#define B_TOT 2
#define TILE_E 64
#define NBLK ((E_TOT + TILE_E - 1) / TILE_E)     // 782
#define TILE_E2 32
#define NBLK2 ((E_TOT + TILE_E2 - 1) / TILE_E2)  // 1563
#define TPAD 67

typedef _Float16 half_t;
typedef __attribute__((ext_vector_type(4))) _Float16 h4;
typedef __attribute__((ext_vector_type(8))) _Float16 h8;
typedef __attribute__((ext_vector_type(4))) float f32x4;

__device__ __forceinline__ float sigmoidf_(float x) {
    return 1.0f / (1.0f + __expf(-x));
}
__device__ __forceinline__ h8 habs8(h8 x) {
    union { h8 h; unsigned int u[4]; } v;
    v.h = x;
#pragma unroll
    for (int i = 0; i < 4; ++i) v.u[i] &= 0x7FFF7FFFu;
    return v.h;
}
__device__ __forceinline__ h8 hmax0(h8 x) {
#if defined(__has_builtin) && __has_builtin(__builtin_elementwise_max)
    h8 z = {};
    return __builtin_elementwise_max(x, z);
#else
    h8 r;
#pragma unroll
    for (int j = 0; j < 8; ++j) r[j] = (x[j] > (half_t)0) ? x[j] : (half_t)0;
    return r;
#endif
}

// ---------------------------------------------------------------------------
// weight arena offsets (halves)
// ---------------------------------------------------------------------------
#define OFF_W1E   0
#define OFF_W1P   8192
#define OFF_WTE2  16384
#define OFF_WTP2  98304
#define OFF_WHA   180224
#define OFF_WHB   221184
#define OFF_WTA   262144
#define OFF_WTB   266240
#define OFF_WTAF  270336
#define OFF_WTBF  286720
#define WARENA_N  303104

__global__ __launch_bounds__(256)
void wprep_k(half_t* __restrict__ wa_,
             const float* __restrict__ w_e1, const float* __restrict__ w_p1,
             const float* __restrict__ w_e2, const float* __restrict__ w_p2,
             const float* __restrict__ wat,  const float* __restrict__ wbt,
             const float* __restrict__ wa,   const float* __restrict__ wb,
             const float* __restrict__ wal,  const float* __restrict__ wbl,
             const float* __restrict__ waf,  const float* __restrict__ wbf)
{
    int idx = blockIdx.x * 256 + threadIdx.x;
    switch (blockIdx.y) {
    case 0: if (idx < 8192) { int o = idx >> 6, k = idx & 63, s = k >> 3, cc = k & 7;
            float v = (s < 5 && cc < 5) ? w_e1[o * 25 + cc * 5 + s] : 0.f;
            wa_[OFF_W1E + idx] = (half_t)v; } break;
    case 1: if (idx < 8192) { int o = idx >> 6, k = idx & 63, s = k >> 3, cc = k & 7;
            float v = (s < 5 && cc >= 5) ? w_p1[o * 15 + (cc - 5) * 5 + s] : 0.f;
            wa_[OFF_W1P + idx] = (half_t)v; } break;
    case 2: if (idx < 81920) { int o = idx / 640, r = idx % 640, s = r >> 7, c = r & 127;
            wa_[OFF_WTE2 + idx] = (half_t)w_e2[(o * 128 + c) * 5 + s]; } break;
    case 3: if (idx < 81920) { int o = idx / 640, r = idx % 640, s = r >> 7, c = r & 127;
            wa_[OFF_WTP2 + idx] = (half_t)w_p2[(o * 128 + c) * 5 + s]; } break;
    case 4: if (idx < 40960) { int o = idx / 320, r = idx % 320, s = r >> 6, c = r & 63;
            float v = (o < 64) ? (s == 0 ? wal[o * 64 + c] : 0.f)
                               : wat[((o - 64) * 64 + c) * 5 + s];
            wa_[OFF_WHA + idx] = (half_t)v; } break;
    case 5: if (idx < 40960) { int o = idx / 320, r = idx % 320, s = r >> 6, c = r & 63;
            float v = (o < 64) ? (s == 0 ? wbl[o * 64 + c] : 0.f)
                               : wbt[((o - 64) * 64 + c) * 5 + s];
            wa_[OFF_WHB + idx] = (half_t)v; } break;
    case 6: if (idx < 4096)  wa_[OFF_WTA  + idx] = (half_t)wa[idx];  break;
    case 7: if (idx < 4096)  wa_[OFF_WTB  + idx] = (half_t)wb[idx];  break;
    case 8: if (idx < 16384) wa_[OFF_WTAF + idx] = (half_t)waf[idx]; break;
    case 9: if (idx < 16384) wa_[OFF_WTBF + idx] = (half_t)wbf[idx]; break;
    }
}

// ---------------------------------------------------------------------------
// transpose fe (b, 8, E) -> fe_t (b, E, 8) f32
// ---------------------------------------------------------------------------
__global__ __launch_bounds__(256)
void transpose_in_k(const float* __restrict__ fe, float* __restrict__ fet)
{
    int b = blockIdx.z;
    int e = blockIdx.x * 256 + threadIdx.x;
    if (e >= E_TOT) return;
    float v[8];
#pragma unroll
    for (int c = 0; c < 8; ++c)
        v[c] = fe[((long)b * 8 + c) * E_TOT + e];
    float4* dst = (float4*)&fet[((long)b * E_TOT + e) * 8];
    dst[0] = make_float4(v[0], v[1], v[2], v[3]);
    dst[1] = make_float4(v[4], v[5], v[6], v[7]);
}

// ---------------------------------------------------------------------------
// layer-1 both branches: shared G, K=64, 8 waves (0-3 edge, 4-7 point)
// ---------------------------------------------------------------------------
__global__ __launch_bounds__(512)
void mesh1_both_k(const float* __restrict__ fet, const int* __restrict__ gemm,
                  const half_t* __restrict__ war,
                  const float* __restrict__ be1, const float* __restrict__ bp1,
                  half_t* __restrict__ tmpe, half_t* __restrict__ tmpp,
                  float* __restrict__ parte, float* __restrict__ partp)
{
    __shared__ h8 Gl[64 * 8];
    __shared__ int nidx[64][4];

    const int tid  = threadIdx.x;
    const int b    = blockIdx.y;
    const int e0   = blockIdx.x * TILE_E;
    const int lane = tid & 63;
    const int wv   = tid >> 6;
    const int l15  = lane & 15;
    const int kg   = lane >> 4;
    const int br   = wv >> 2;
    const int o0   = (wv & 3) * 32;

    const float* xb = fet + (long)b * E_TOT * 8;

    if (tid < 256) {
        int e = tid >> 2, s = tid & 3;
        int eg = e0 + e;
        nidx[e][s] = (eg < E_TOT) ? gemm[((long)b * E_TOT + eg) * 4 + s] : 0;
    }
    __syncthreads();

    {
        int e = tid >> 3, g = tid & 7;
        int eg = e0 + e;
        int se = (eg < E_TOT) ? eg : 0;
        h8 r;
        if (g == 0) {
            const float* p = xb + (long)se * 8;
            float4 v0 = *(const float4*)p, v1 = *(const float4*)(p + 4);
            r[0] = (half_t)v0.x; r[1] = (half_t)v0.y; r[2] = (half_t)v0.z; r[3] = (half_t)v0.w;
            r[4] = (half_t)v1.x; r[5] = (half_t)v1.y; r[6] = (half_t)v1.z; r[7] = (half_t)v1.w;
        } else if (g <= 4) {
            int ia = (g == 1 || g == 3) ? 0 : 1;
            const float* pa = xb + (long)nidx[e][ia] * 8;
            const float* pb = xb + (long)nidx[e][ia + 2] * 8;
            float4 a0 = *(const float4*)pa, a1 = *(const float4*)(pa + 4);
            float4 b0 = *(const float4*)pb, b1 = *(const float4*)(pb + 4);
            float aa[8] = {a0.x, a0.y, a0.z, a0.w, a1.x, a1.y, a1.z, a1.w};
            float bb[8] = {b0.x, b0.y, b0.z, b0.w, b1.x, b1.y, b1.z, b1.w};
            if (g <= 2) {
#pragma unroll
                for (int j = 0; j < 8; ++j) r[j] = (half_t)(aa[j] + bb[j]);
            } else {
#pragma unroll
                for (int j = 0; j < 8; ++j) r[j] = (half_t)fabsf(aa[j] - bb[j]);
            }
        } else {
#pragma unroll
            for (int j = 0; j < 8; ++j) r[j] = (half_t)0.f;
        }
        Gl[(e * 8 + g) ^ (e & 7)] = r;
    }
    __syncthreads();

    f32x4 acc[4][2];
#pragma unroll
    for (int mt = 0; mt < 4; ++mt)
#pragma unroll
        for (int nt = 0; nt < 2; ++nt)
#pragma unroll
            for (int j = 0; j < 4; ++j) acc[mt][nt][j] = 0.f;

    const half_t* wt = war + (br ? OFF_W1P : OFF_W1E);
#pragma unroll
    for (int ks = 0; ks < 2; ++ks) {
        h8 bw[2];
#pragma unroll
        for (int nt = 0; nt < 2; ++nt)
            bw[nt] = *(const h8*)(wt + (long)(o0 + nt * 16 + l15) * 64 + ks * 32 + kg * 8);
#pragma unroll
        for (int mt = 0; mt < 4; ++mt) {
            int row = mt * 16 + l15;
            h8 a = Gl[row * 8 + ((ks * 4 + kg) ^ (row & 7))];
#pragma unroll
            for (int nt = 0; nt < 2; ++nt)
                acc[mt][nt] = __builtin_amdgcn_mfma_f32_16x16x32_f16(a, bw[nt], acc[mt][nt], 0, 0, 0);
        }
    }

    const float* bias = br ? bp1 : be1;
    half_t* yb = (br ? tmpp : tmpe) + (long)b * E_TOT * 128;
    float* part = br ? partp : parte;
    float bv[2], s1[2], s2[2];
#pragma unroll
    for (int nt = 0; nt < 2; ++nt) {
        bv[nt] = bias[o0 + nt * 16 + l15];
        s1[nt] = 0.f; s2[nt] = 0.f;
    }
#pragma unroll
    for (int mt = 0; mt < 4; ++mt) {
        int ebase = e0 + mt * 16 + (kg << 2);
#pragma unroll
        for (int j = 0; j < 4; ++j) {
            if (ebase + j < E_TOT) {
#pragma unroll
                for (int nt = 0; nt < 2; ++nt) {
                    float v = acc[mt][nt][j] + bv[nt];
                    yb[(long)(ebase + j) * 128 + o0 + nt * 16 + l15] = (half_t)v;
                    s1[nt] += v; s2[nt] += v * v;
                }
            }
        }
    }
#pragma unroll
    for (int nt = 0; nt < 2; ++nt) {
        s1[nt] += __shfl_xor(s1[nt], 16); s1[nt] += __shfl_xor(s1[nt], 32);
        s2[nt] += __shfl_xor(s2[nt], 16); s2[nt] += __shfl_xor(s2[nt], 32);
    }
    if (lane < 16) {
        long pb = ((long)b * NBLK + blockIdx.x) * 128;
#pragma unroll
        for (int nt = 0; nt < 2; ++nt) {
            part[(pb + o0 + nt * 16 + lane) * 2 + 0] = s1[nt];
            part[(pb + o0 + nt * 16 + lane) * 2 + 1] = s2[nt];
        }
    }
}

// ---------------------------------------------------------------------------
// layer-2 mesh conv — R5-best 5-phase schedule, fused input norm, re-tiled:
// 256 threads / 4 waves, TILE_E2=32, LDS 16.9 KB -> 8 blocks/CU.
// Each wave owns 32 outputs (NT=2); partials strided by NBLK2.
// ---------------------------------------------------------------------------
__global__ __launch_bounds__(256, 8)
void mesh2_k(const half_t* __restrict__ tmp1e, const half_t* __restrict__ tmp1p,
             const half_t* __restrict__ statshe, const half_t* __restrict__ statshp,
             const int* __restrict__ gemm, const half_t* __restrict__ war,
             const float* __restrict__ be, const float* __restrict__ bp,
             half_t* __restrict__ tmp2e, half_t* __restrict__ tmp2p,
             float* __restrict__ parte, float* __restrict__ partp)
{
    __shared__ h8 GlA[TILE_E2 * 16];   // 8 KB
    __shared__ h8 GlB[TILE_E2 * 16];   // 8 KB
    __shared__ int nidx[TILE_E2][4];

    const int tid  = threadIdx.x;
    const int br   = blockIdx.y;
    const int b    = blockIdx.z;
    const int e0   = blockIdx.x * TILE_E2;
    const int lane = tid & 63;
    const int wv   = tid >> 6;         // 0..3
    const int l15  = lane & 15;
    const int kg   = lane >> 4;
    const int o0   = wv * 32;

    const half_t* xb = (br ? tmp1p : tmp1e) + (long)b * E_TOT * 128;
    const half_t* sh = (br ? statshp : statshe) + (long)b * 256;
    const half_t* wt = war + (br ? OFF_WTP2 : OFF_WTE2);

    const int tc0 = tid & 15;
    const h8 sc8 = *(const h8*)(sh + tc0 * 8);
    const h8 sf8 = *(const h8*)(sh + 128 + tc0 * 8);

    if (tid < TILE_E2 * 4) {
        int e = tid >> 2, s = tid & 3;
        int eg = e0 + e;
        nidx[e][s] = (eg < E_TOT) ? gemm[((long)b * E_TOT + eg) * 4 + s] : 0;
    }

    auto nrm = [&](h8 v) -> h8 { return hmax0(v * sc8 + sf8); };

    auto stage_self = [&](h8* dst) {
#pragma unroll
        for (int t = 0; t < 2; ++t) {
            int q = t * 256 + tid;
            int e = q >> 4, c8 = q & 15;
            int eg = e0 + e;
            int se = (eg < E_TOT) ? eg : 0;
            dst[(e * 16 + c8) ^ (e & 7)] = nrm(*(const h8*)(xb + (long)se * 128 + c8 * 8));
        }
    };
    auto stage_pair = [&](h8* dstS, h8* dstD, int ia, int ib) {
#pragma unroll
        for (int t = 0; t < 2; ++t) {
            int q = t * 256 + tid;
            int e = q >> 4, c8 = q & 15;
            int na = nidx[e][ia], nb = nidx[e][ib];
            h8 a  = nrm(*(const h8*)(xb + (long)na * 128 + c8 * 8));
            h8 bq = nrm(*(const h8*)(xb + (long)nb * 128 + c8 * 8));
            int slot = (e * 16 + c8) ^ (e & 7);
            dstS[slot] = a + bq;
            dstD[slot] = habs8(a - bq);
        }
    };

    f32x4 acc[2][2];
#pragma unroll
    for (int mt = 0; mt < 2; ++mt)
#pragma unroll
        for (int nt = 0; nt < 2; ++nt)
#pragma unroll
            for (int j = 0; j < 4; ++j) acc[mt][nt][j] = 0.f;

    auto compute_chunk = [&](const h8* buf, int s) {
#pragma unroll
        for (int ks = 0; ks < 4; ++ks) {
            h8 bw0 = *(const h8*)(wt + ((long)(o0 + l15) * 5 + s) * 128 + ks * 32 + kg * 8);
            h8 bw1 = *(const h8*)(wt + ((long)(o0 + 16 + l15) * 5 + s) * 128 + ks * 32 + kg * 8);
#pragma unroll
            for (int mt = 0; mt < 2; ++mt) {
                int row = mt * 16 + l15;
                h8 a = buf[row * 16 + ((ks * 4 + kg) ^ (row & 7))];
                acc[mt][0] = __builtin_amdgcn_mfma_f32_16x16x32_f16(a, bw0, acc[mt][0], 0, 0, 0);
                acc[mt][1] = __builtin_amdgcn_mfma_f32_16x16x32_f16(a, bw1, acc[mt][1], 0, 0, 0);
            }
        }
    };

    __syncthreads();                    // nidx ready
    stage_self(GlA);
    __syncthreads();
    compute_chunk(GlA, 0);
    __syncthreads();
    stage_pair(GlA, GlB, 0, 2);
    __syncthreads();
    compute_chunk(GlA, 1);
    compute_chunk(GlB, 3);
    __syncthreads();
    stage_pair(GlA, GlB, 1, 3);
    __syncthreads();
    compute_chunk(GlA, 2);
    compute_chunk(GlB, 4);

    const float* bias = br ? bp : be;
    half_t* yb = (br ? tmp2p : tmp2e) + (long)b * E_TOT * 128;
    float* part = br ? partp : parte;
    float bv[2], s1[2], s2[2];
#pragma unroll
    for (int nt = 0; nt < 2; ++nt) {
        bv[nt] = bias[o0 + nt * 16 + l15];
        s1[nt] = 0.f; s2[nt] = 0.f;
    }
#pragma unroll
    for (int mt = 0; mt < 2; ++mt) {
        int ebase = e0 + mt * 16 + (kg << 2);
#pragma unroll
        for (int j = 0; j < 4; ++j) {
            if (ebase + j < E_TOT) {
#pragma unroll
                for (int nt = 0; nt < 2; ++nt) {
                    float v = acc[mt][nt][j] + bv[nt];
                    yb[(long)(ebase + j) * 128 + o0 + nt * 16 + l15] = (half_t)v;
                    s1[nt] += v; s2[nt] += v * v;
                }
            }
        }
    }
#pragma unroll
    for (int nt = 0; nt < 2; ++nt) {
        s1[nt] += __shfl_xor(s1[nt], 16); s1[nt] += __shfl_xor(s1[nt], 32);
        s2[nt] += __shfl_xor(s2[nt], 16); s2[nt] += __shfl_xor(s2[nt], 32);
    }
    if (lane < 16) {
        long pb = ((long)b * NBLK2 + blockIdx.x) * 128;
#pragma unroll
        for (int nt = 0; nt < 2; ++nt) {
            part[(pb + o0 + nt * 16 + lane) * 2 + 0] = s1[nt];
            part[(pb + o0 + nt * 16 + lane) * 2 + 1] = s2[nt];
        }
    }
}

// ---------------------------------------------------------------------------
// FUSED normres + xall (unchanged from R9)
// ---------------------------------------------------------------------------
__global__ __launch_bounds__(512)
void normres_xall_k(const half_t* __restrict__ tmp2e, const half_t* __restrict__ tmp2p,
                    const half_t* __restrict__ tmp1e, const half_t* __restrict__ tmp1p,
                    const half_t* __restrict__ sh1e, const half_t* __restrict__ sh1p,
                    const half_t* __restrict__ sh2e, const half_t* __restrict__ sh2p,
                    const half_t* __restrict__ war,
                    const float* __restrict__ ba, const float* __restrict__ bb,
                    float* __restrict__ outb,
                    half_t* __restrict__ x2e, half_t* __restrict__ x2p,
                    half_t* __restrict__ xall)
{
    __shared__ float Tf[128 * TPAD];
    __shared__ h8 X2t[1024];

    const int tid  = threadIdx.x;
    const int br   = blockIdx.y;
    const int b    = blockIdx.z;
    const int e0   = blockIdx.x * TILE_E;
    const int lane = tid & 63;
    const int wv   = tid >> 6;
    const int l15  = lane & 15;
    const int kg   = lane >> 4;

    const half_t* t2 = (br ? tmp2p : tmp2e) + (long)b * E_TOT * 128;
    const half_t* t1 = (br ? tmp1p : tmp1e) + (long)b * E_TOT * 128;
    const half_t* s1p = (br ? sh1p : sh1e) + (long)b * 256;
    const half_t* s2p = (br ? sh2p : sh2e) + (long)b * 256;
    half_t* x2g = (br ? x2p : x2e) + (long)b * E_TOT * 128;

    const int tc0 = tid & 15;
    const h8 sc1 = *(const h8*)(s1p + tc0 * 8);
    const h8 sf1 = *(const h8*)(s1p + 128 + tc0 * 8);
    const h8 sc2 = *(const h8*)(s2p + tc0 * 8);
    const h8 sf2 = *(const h8*)(s2p + 128 + tc0 * 8);

#pragma unroll
    for (int t = 0; t < 2; ++t) {
        int q = t * 512 + tid;
        int e = q >> 4;
        int eg = e0 + e;
        int se = (eg < E_TOT) ? eg : (E_TOT - 1);
        h8 v2 = *(const h8*)(t2 + (long)se * 128 + tc0 * 8);
        h8 v1 = *(const h8*)(t1 + (long)se * 128 + tc0 * 8);
        h8 x1 = hmax0(v1 * sc1 + sf1);
        h8 x2 = hmax0(v2 * sc2 + sf2 + x1);
        X2t[(e * 16 + tc0) ^ (e & 7)] = x2;
        if (eg < E_TOT) *(h8*)(x2g + (long)eg * 128 + tc0 * 8) = x2;
#pragma unroll
        for (int j = 0; j < 8; ++j)
            Tf[(tc0 * 8 + j) * TPAD + e] = (float)x2[j];
    }
    __syncthreads();

#pragma unroll
    for (int i = 0; i < 4; ++i) {
        int task = i * 512 + tid;
        int cl = task >> 4, eq = task & 15;
        int e4 = e0 + eq * 4;
        float4 v = *(const float4*)&Tf[cl * TPAD + eq * 4];
        int cglob = br * 128 + cl;
        long obase = ((long)b * 384 + cglob) * E_TOT + e4;
        if (e4 + 3 < E_TOT) {
            *(float4*)&outb[obase] = v;
        } else {
            const float* vp = &v.x;
            for (int j = 0; j < 4; ++j)
                if (e4 + j < E_TOT) outb[obase + j] = vp[j];
        }
    }

    const int eoff = (wv & 3) * 16;
    const int og   = wv >> 2;
    const half_t* wt = war + (br ? OFF_WTB : OFF_WTA);
    f32x4 acc;
#pragma unroll
    for (int j = 0; j < 4; ++j) acc[j] = 0.f;
#pragma unroll
    for (int ks = 0; ks < 4; ++ks) {
        h8 bw = *(const h8*)(wt + (long)(og * 16 + l15) * 128 + ks * 32 + kg * 8);
        int row = eoff + l15;
        h8 a = X2t[row * 16 + ((ks * 4 + kg) ^ (row & 7))];
        acc = __builtin_amdgcn_mfma_f32_16x16x32_f16(a, bw, acc, 0, 0, 0);
    }
    float bv = (br ? bb : ba)[og * 16 + l15];
    half_t* yall = xall + (long)b * E_TOT * 64;
#pragma unroll
    for (int j = 0; j < 4; ++j) {
        int e = e0 + eoff + (kg << 2) + j;
        if (e < E_TOT)
            yall[(long)e * 64 + br * 32 + og * 16 + l15] = (half_t)(acc[j] + bv);
    }
}

// ---------------------------------------------------------------------------
// FUSED decoder heads + gates (unchanged from R9)
// ---------------------------------------------------------------------------
__global__ __launch_bounds__(512)
void heads_gates_k(const half_t* __restrict__ xall, const int* __restrict__ gemm,
                   const half_t* __restrict__ war,
                   const float* __restrict__ bal, const float* __restrict__ bbl,
                   const float* __restrict__ bat, const float* __restrict__ bbt,
                   const float* __restrict__ baf, const float* __restrict__ bbf,
                   half_t* __restrict__ gA, half_t* __restrict__ gB,
                   float* __restrict__ parte, float* __restrict__ partp)
{
    __shared__ h8 arena[2048];
    __shared__ int nidx[64][4];

    const int tid  = threadIdx.x;
    const int b    = blockIdx.y;
    const int e0   = blockIdx.x * TILE_E;
    const int lane = tid & 63;
    const int wv   = tid >> 6;
    const int hd   = wv >> 2;
    const int o0   = (wv & 3) * 32;
    const int l15  = lane & 15;
    const int kg   = lane >> 4;

    h8* C0 = arena;
    h8* C1 = arena + 512;
    h8* C2 = arena + 1024;

    const half_t* xb = xall + (long)b * E_TOT * 64;

    if (tid < 256) {
        int e = tid >> 2, s = tid & 3;
        int eg = e0 + e;
        nidx[e][s] = (eg < E_TOT) ? gemm[((long)b * E_TOT + eg) * 4 + s] : 0;
    }
    __syncthreads();

    const int te = tid >> 3, tc = tid & 7;
    const int tslot = (te * 8 + tc) ^ (te & 7);

    {
        int eg = e0 + te;
        int se = (eg < E_TOT) ? eg : 0;
        C0[tslot] = *(const h8*)(xb + (long)se * 64 + tc * 8);
    }
    h8 rA, rB;
    {
        rA = *(const h8*)(xb + (long)nidx[te][0] * 64 + tc * 8);
        rB = *(const h8*)(xb + (long)nidx[te][2] * 64 + tc * 8);
    }
    __syncthreads();

    f32x4 acc[4][2];
#pragma unroll
    for (int mt = 0; mt < 4; ++mt)
#pragma unroll
        for (int nt = 0; nt < 2; ++nt)
#pragma unroll
            for (int j = 0; j < 4; ++j) acc[mt][nt][j] = 0.f;

    const half_t* wt = war + (hd ? OFF_WHB : OFF_WHA);
    auto chunk = [&](const h8* buf, int s) {
#pragma unroll
        for (int ks = 0; ks < 2; ++ks) {
            h8 bw0 = *(const h8*)(wt + ((long)(o0 + l15) * 5 + s) * 64 + ks * 32 + kg * 8);
            h8 bw1 = *(const h8*)(wt + ((long)(o0 + 16 + l15) * 5 + s) * 64 + ks * 32 + kg * 8);
#pragma unroll
            for (int mt = 0; mt < 4; ++mt) {
                int row = mt * 16 + l15;
                h8 a = buf[row * 8 + ((ks * 4 + kg) ^ (row & 7))];
                acc[mt][0] = __builtin_amdgcn_mfma_f32_16x16x32_f16(a, bw0, acc[mt][0], 0, 0, 0);
                acc[mt][1] = __builtin_amdgcn_mfma_f32_16x16x32_f16(a, bw1, acc[mt][1], 0, 0, 0);
            }
        }
    };

    chunk(C0, 0);
    __syncthreads();
    {
        C1[tslot] = rA + rB;
        C2[tslot] = habs8(rA - rB);
        rA = *(const h8*)(xb + (long)nidx[te][1] * 64 + tc * 8);
        rB = *(const h8*)(xb + (long)nidx[te][3] * 64 + tc * 8);
    }
    __syncthreads();
    chunk(C1, 1);
    chunk(C2, 3);
    __syncthreads();
    {
        C1[tslot] = rA + rB;
        C2[tslot] = habs8(rA - rB);
    }
    __syncthreads();
    chunk(C1, 2);
    chunk(C2, 4);
    __syncthreads();

    {
        half_t* X = (half_t*)(arena + hd * 1024);
        float bv[2];
#pragma unroll
        for (int nt = 0; nt < 2; ++nt) {
            int o = o0 + nt * 16 + l15;
            bv[nt] = (o < 64) ? (hd ? bbl[o] : bal[o]) : (hd ? bbt[o - 64] : bat[o - 64]);
        }
#pragma unroll
        for (int mt = 0; mt < 4; ++mt) {
#pragma unroll
            for (int j = 0; j < 4; ++j) {
                int e = mt * 16 + (kg << 2) + j;
#pragma unroll
                for (int nt = 0; nt < 2; ++nt) {
                    int c = o0 + nt * 16 + l15;
                    int slot = (e * 16 + (c >> 3)) ^ (e & 7);
                    X[slot * 8 + (c & 7)] = (half_t)(acc[mt][nt][j] + bv[nt]);
                }
            }
        }
    }
    __syncthreads();

    f32x4 g[4][2];
#pragma unroll
    for (int mt = 0; mt < 4; ++mt)
#pragma unroll
        for (int nt = 0; nt < 2; ++nt)
#pragma unroll
            for (int j = 0; j < 4; ++j) g[mt][nt][j] = 0.f;

    const half_t* wtg = war + (hd ? OFF_WTBF : OFF_WTAF);
    const h8* X = arena + hd * 1024;
#pragma unroll
    for (int ks = 0; ks < 4; ++ks) {
        h8 bw0 = *(const h8*)(wtg + (long)(o0 + l15) * 128 + ks * 32 + kg * 8);
        h8 bw1 = *(const h8*)(wtg + (long)(o0 + 16 + l15) * 128 + ks * 32 + kg * 8);
#pragma unroll
        for (int mt = 0; mt < 4; ++mt) {
            int row = mt * 16 + l15;
            h8 a = X[row * 16 + ((ks * 4 + kg) ^ (row & 7))];
            g[mt][0] = __builtin_amdgcn_mfma_f32_16x16x32_f16(a, bw0, g[mt][0], 0, 0, 0);
            g[mt][1] = __builtin_amdgcn_mfma_f32_16x16x32_f16(a, bw1, g[mt][1], 0, 0, 0);
        }
    }

    const float* biasg = hd ? bbf : baf;
    half_t* yb = (hd ? gB : gA) + (long)b * E_TOT * 128;
    float* part = hd ? partp : parte;
    float bg[2] = {biasg[o0 + l15], biasg[o0 + 16 + l15]};
    float s1[2] = {0.f, 0.f}, s2[2] = {0.f, 0.f};
#pragma unroll
    for (int mt = 0; mt < 4; ++mt) {
        int ebase = e0 + mt * 16 + (kg << 2);
#pragma unroll
        for (int j = 0; j < 4; ++j) {
            if (ebase + j < E_TOT) {
#pragma unroll
                for (int nt = 0; nt < 2; ++nt) {
                    float v = g[mt][nt][j] + bg[nt];
                    yb[(long)(ebase + j) * 128 + o0 + nt * 16 + l15] = (half_t)v;
                    s1[nt] += v; s2[nt] += v * v;
                }
            }
        }
    }
#pragma unroll
    for (int nt = 0; nt < 2; ++nt) {
        s1[nt] += __shfl_xor(s1[nt], 16); s1[nt] += __shfl_xor(s1[nt], 32);
        s2[nt] += __shfl_xor(s2[nt], 16); s2[nt] += __shfl_xor(s2[nt], 32);
    }
    if (lane < 16) {
        long pb = ((long)b * NBLK + blockIdx.x) * 128;
#pragma unroll
        for (int nt = 0; nt < 2; ++nt) {
            part[(pb + o0 + nt * 16 + lane) * 2 + 0] = s1[nt];
            part[(pb + o0 + nt * 16 + lane) * 2 + 1] = s2[nt];
        }
    }
}

// ---------------------------------------------------------------------------
// stats finalize (nblk-parameterized): f32 (mean,rstd) + f16 (scale,shift)
// ---------------------------------------------------------------------------
__global__ __launch_bounds__(256)
void stats2_k(const float* __restrict__ parte, const float* __restrict__ partp,
              int nblk,
              float* __restrict__ statse, float* __restrict__ statsp,
              half_t* __restrict__ statshe, half_t* __restrict__ statshp)
{
    int g = blockIdx.x;
    int br = g >> 8, rem = g & 255, b = rem >> 7, o = rem & 127;
    const float* part = br ? partp : parte;
    float* stats = br ? statsp : statse;
    half_t* statsh = br ? statshp : statshe;
    int tid = threadIdx.x;
    float s1 = 0.f, s2 = 0.f;
    for (int k = tid; k < nblk; k += 256) {
        long base = (((long)b * nblk + k) * 128 + o) * 2;
        s1 += part[base];
        s2 += part[base + 1];
    }
#pragma unroll
    for (int d = 1; d < 64; d <<= 1) {
        s1 += __shfl_xor(s1, d);
        s2 += __shfl_xor(s2, d);
    }
    __shared__ float r1[4], r2[4];
    int wv = tid >> 6;
    if ((tid & 63) == 0) { r1[wv] = s1; r2[wv] = s2; }
    __syncthreads();
    if (tid == 0) {
        s1 = r1[0] + r1[1] + r1[2] + r1[3];
        s2 = r2[0] + r2[1] + r2[2] + r2[3];
        float mean = s1 / (float)E_TOT;
        float var  = s2 / (float)E_TOT - mean * mean;
        var = fmaxf(var, 0.f);
        float rstd = rsqrtf(var + 1e-5f);
        stats[(b * 128 + o) * 2 + 0] = mean;
        stats[(b * 128 + o) * 2 + 1] = rstd;
        statsh[b * 256 + o]       = (half_t)rstd;
        statsh[b * 256 + 128 + o] = (half_t)(-mean * rstd);
    }
}

// ---------------------------------------------------------------------------
// fused gates-norm + softmax2 + aggregate (unchanged)
// ---------------------------------------------------------------------------
__global__ __launch_bounds__(256)
void gate_agg2_k(const half_t* __restrict__ tA, const half_t* __restrict__ tB,
                 const float* __restrict__ statsA, const float* __restrict__ statsB,
                 const half_t* __restrict__ x2e, const half_t* __restrict__ x2p,
                 float* __restrict__ outb)
{
    __shared__ float T[32 * 68];
    int b = blockIdx.z, cg = blockIdx.y;
    int e0 = blockIdx.x * 64;
    int tid = threadIdx.x;
#pragma unroll
    for (int i = 0; i < 2; ++i) {
        int q = tid + i * 256;
        int e = q >> 3, cq = q & 7;
        int eg = e0 + e;
        int se = (eg < E_TOT) ? eg : (E_TOT - 1);
        int c = cg * 32 + cq * 4;
        long base = ((long)b * E_TOT + se) * 128 + c;
        h4 a4 = *(const h4*)&tA[base];
        h4 b4 = *(const h4*)&tB[base];
        h4 xe4 = *(const h4*)&x2e[base];
        h4 xp4 = *(const h4*)&x2p[base];
#pragma unroll
        for (int j = 0; j < 4; ++j) {
            float2 sa = *(const float2*)&statsA[(b * 128 + c + j) * 2];
            float2 sb = *(const float2*)&statsB[(b * 128 + c + j) * 2];
            float na = sigmoidf_(((float)a4[j] - sa.x) * sa.y);
            float nb = sigmoidf_(((float)b4[j] - sb.x) * sb.y);
            float s = sigmoidf_(na - nb);
            T[(cq * 4 + j) * 68 + e] = (float)xe4[j] * s + (float)xp4[j] * (1.f - s);
        }
    }
    __syncthreads();
#pragma unroll
    for (int i = 0; i < 2; ++i) {
        int q = tid + i * 256;
        int cl = q >> 4, eq = q & 15;
        int e4 = e0 + eq * 4;
        int cglob = cg * 32 + cl;
        float4 v = *(const float4*)&T[cl * 68 + eq * 4];
        long ab = ((long)b * 384 + 256 + cglob) * E_TOT + e4;
        if (e4 + 3 < E_TOT) {
            *(float4*)&outb[ab] = v;
        } else {
            const float* vp = &v.x;
            for (int j = 0; j < 4; ++j)
                if (e4 + j < E_TOT) outb[ab + j] = vp[j];
        }
    }
}

// ---------------------------------------------------------------------------
extern "C" void kernel_launch(void* const* d_in, const int* in_sizes, int n_in,
                              void* d_out, int out_size, void* d_ws, size_t ws_size,
                              hipStream_t stream)
{
    const float* fe   = (const float*)d_in[0];
    const int*   gemm = (const int*)  d_in[1];
    const float* w_e1 = (const float*)d_in[2];  const float* b_e1 = (const float*)d_in[3];
    const float* w_p1 = (const float*)d_in[4];  const float* b_p1 = (const float*)d_in[5];
    const float* w_e2 = (const float*)d_in[6];  const float* b_e2 = (const float*)d_in[7];
    const float* w_p2 = (const float*)d_in[8];  const float* b_p2 = (const float*)d_in[9];
    const float* wa   = (const float*)d_in[10]; const float* ba   = (const float*)d_in[11];
    const float* wb   = (const float*)d_in[12]; const float* bb   = (const float*)d_in[13];
    const float* wal  = (const float*)d_in[14]; const float* bal  = (const float*)d_in[15];
    const float* wbl  = (const float*)d_in[16]; const float* bbl  = (const float*)d_in[17];
    const float* wat  = (const float*)d_in[18]; const float* bat  = (const float*)d_in[19];
    const float* wbt  = (const float*)d_in[20]; const float* bbt  = (const float*)d_in[21];
    const float* waf  = (const float*)d_in[22]; const float* baf  = (const float*)d_in[23];
    const float* wbf  = (const float*)d_in[24]; const float* bbf  = (const float*)d_in[25];
    float* out = (float*)d_out;

    const long EB = (long)E_TOT;

    char* wp = (char*)d_ws;
    auto alloc = [&](size_t bytes) -> void* {
        void* r = (void*)wp;
        wp += (bytes + 255) & ~(size_t)255;
        return r;
    };
    float*  FET    = (float*)alloc((size_t)B_TOT * EB * 8 * 4);
    half_t* TMP1_E = (half_t*)alloc((size_t)B_TOT * EB * 128 * 2);
    half_t* TMP1_P = (half_t*)alloc((size_t)B_TOT * EB * 128 * 2);
    half_t* TMP2_E = (half_t*)alloc((size_t)B_TOT * EB * 128 * 2);
    half_t* TMP2_P = (half_t*)alloc((size_t)B_TOT * EB * 128 * 2);
    half_t* X2E    = (half_t*)alloc((size_t)B_TOT * EB * 128 * 2);
    half_t* X2P    = (half_t*)alloc((size_t)B_TOT * EB * 128 * 2);
    half_t* XALL   = (half_t*)alloc((size_t)B_TOT * EB * 64 * 2);
    float*  PART_E = (float*)alloc((size_t)B_TOT * NBLK2 * 128 * 2 * 4);
    float*  PART_P = (float*)alloc((size_t)B_TOT * NBLK2 * 128 * 2 * 4);
    float*  STATSE = (float*)alloc((size_t)B_TOT * 128 * 2 * 4);
    float*  STATSP = (float*)alloc((size_t)B_TOT * 128 * 2 * 4);
    half_t* SH1E   = (half_t*)alloc((size_t)B_TOT * 256 * 2);
    half_t* SH1P   = (half_t*)alloc((size_t)B_TOT * 256 * 2);
    half_t* SH2E   = (half_t*)alloc((size_t)B_TOT * 256 * 2);
    half_t* SH2P   = (half_t*)alloc((size_t)B_TOT * 256 * 2);
    half_t* WAR    = (half_t*)alloc((size_t)WARENA_N * 2);

    if ((size_t)(wp - (char*)d_ws) > ws_size) {
        fprintf(stderr, "kernel_launch: ws too small (%zu < %zu)\n",
                ws_size, (size_t)(wp - (char*)d_ws));
        return;
    }

    dim3 blk256(256), blk512(512);
    dim3 gI(NBLK, B_TOT);
    dim3 gE2(NBLK, 2, B_TOT);
    dim3 gM2(NBLK2, 2, B_TOT);
    dim3 gT((E_TOT + 255) / 256, 1, B_TOT);
    dim3 gN4(NBLK, 4, B_TOT);

    // 1-2: prep
    wprep_k<<<dim3(320, 10, 1), blk256, 0, stream>>>(WAR,
        w_e1, w_p1, w_e2, w_p2, wat, wbt, wa, wb, wal, wbl, waf, wbf);
    transpose_in_k<<<gT, blk256, 0, stream>>>(fe, FET);

    // 3-4: layer 1 (both branches) + stats
    mesh1_both_k<<<gI, blk512, 0, stream>>>(FET, gemm, WAR, b_e1, b_p1,
        TMP1_E, TMP1_P, PART_E, PART_P);
    stats2_k<<<512, blk256, 0, stream>>>(PART_E, PART_P, NBLK, STATSE, STATSP, SH1E, SH1P);

    // 5-6: layer 2 (fused input-norm, 8 blocks/CU tiling) + stats
    mesh2_k<<<gM2, blk256, 0, stream>>>(TMP1_E, TMP1_P, SH1E, SH1P, gemm, WAR,
        b_e2, b_p2, TMP2_E, TMP2_P, PART_E, PART_P);
    stats2_k<<<512, blk256, 0, stream>>>(PART_E, PART_P, NBLK2, STATSE, STATSP, SH2E, SH2P);

    // 7: normres + xall
    normres_xall_k<<<gE2, blk512, 0, stream>>>(TMP2_E, TMP2_P, TMP1_E, TMP1_P,
        SH1E, SH1P, SH2E, SH2P, WAR, ba, bb, out, X2E, X2P, XALL);

    // 8-9: decoder heads + gates (fused) + gate stats
    heads_gates_k<<<gI, blk512, 0, stream>>>(XALL, gemm, WAR,
        bal, bbl, bat, bbt, baf, bbf, TMP1_E, TMP1_P, PART_E, PART_P);
    stats2_k<<<512, blk256, 0, stream>>>(PART_E, PART_P, NBLK, STATSE, STATSP, SH1E, SH1P);

    // 10: aggregate
    gate_agg2_k<<<gN4, blk256, 0, stream>>>(TMP1_E, TMP1_P, STATSE, STATSP,
        X2E, X2P, out);
}

// Round 11
// 306.121 us; speedup vs baseline: 1.1250x; 1.1250x over previous
//
#include <hip/hip_runtime.h>
#include <cstdio>
#include <math.h>

// ---------------------------------------------------------------------------
// MeshEncoderDecoder — round 11: mesh2 reverted to R9-exact (512thr/TILE_E=64,
// fused input-norm, 4 blocks/CU — measured optimum across R5-R10 variants).
// transpose fused into wprep (10 launches).
// ---------------------------------------------------------------------------

#define E_TOT 50000
#define B_TOT 2
#define TILE_E 64
#define NBLK ((E_TOT + TILE_E - 1) / TILE_E)     // 782
#define TPAD 67

typedef _Float16 half_t;
typedef __attribute__((ext_vector_type(4))) _Float16 h4;
typedef __attribute__((ext_vector_type(8))) _Float16 h8;
typedef __attribute__((ext_vector_type(4))) float f32x4;

__device__ __forceinline__ float sigmoidf_(float x) {
    return 1.0f / (1.0f + __expf(-x));
}
__device__ __forceinline__ h8 habs8(h8 x) {
    union { h8 h; unsigned int u[4]; } v;
    v.h = x;
#pragma unroll
    for (int i = 0; i < 4; ++i) v.u[i] &= 0x7FFF7FFFu;
    return v.h;
}
__device__ __forceinline__ h8 hmax0(h8 x) {
#if defined(__has_builtin) && __has_builtin(__builtin_elementwise_max)
    h8 z = {};
    return __builtin_elementwise_max(x, z);
#else
    h8 r;
#pragma unroll
    for (int j = 0; j < 8; ++j) r[j] = (x[j] > (half_t)0) ? x[j] : (half_t)0;
    return r;
#endif
}

// ---------------------------------------------------------------------------
// weight arena offsets (halves)
// ---------------------------------------------------------------------------
#define OFF_W1E   0
#define OFF_W1P   8192
#define OFF_WTE2  16384
#define OFF_WTP2  98304
#define OFF_WHA   180224
#define OFF_WHB   221184
#define OFF_WTA   262144
#define OFF_WTB   266240
#define OFF_WTAF  270336
#define OFF_WTBF  286720
#define WARENA_N  303104

// prep: weight convert/reorder (cases 0-9) + fe transpose (cases 10-11)
__global__ __launch_bounds__(256)
void wprep_k(half_t* __restrict__ wa_, float* __restrict__ fet,
             const float* __restrict__ fe,
             const float* __restrict__ w_e1, const float* __restrict__ w_p1,
             const float* __restrict__ w_e2, const float* __restrict__ w_p2,
             const float* __restrict__ wat,  const float* __restrict__ wbt,
             const float* __restrict__ wa,   const float* __restrict__ wb,
             const float* __restrict__ wal,  const float* __restrict__ wbl,
             const float* __restrict__ waf,  const float* __restrict__ wbf)
{
    int idx = blockIdx.x * 256 + threadIdx.x;
    switch (blockIdx.y) {
    case 0: if (idx < 8192) { int o = idx >> 6, k = idx & 63, s = k >> 3, cc = k & 7;
            float v = (s < 5 && cc < 5) ? w_e1[o * 25 + cc * 5 + s] : 0.f;
            wa_[OFF_W1E + idx] = (half_t)v; } break;
    case 1: if (idx < 8192) { int o = idx >> 6, k = idx & 63, s = k >> 3, cc = k & 7;
            float v = (s < 5 && cc >= 5) ? w_p1[o * 15 + (cc - 5) * 5 + s] : 0.f;
            wa_[OFF_W1P + idx] = (half_t)v; } break;
    case 2: if (idx < 81920) { int o = idx / 640, r = idx % 640, s = r >> 7, c = r & 127;
            wa_[OFF_WTE2 + idx] = (half_t)w_e2[(o * 128 + c) * 5 + s]; } break;
    case 3: if (idx < 81920) { int o = idx / 640, r = idx % 640, s = r >> 7, c = r & 127;
            wa_[OFF_WTP2 + idx] = (half_t)w_p2[(o * 128 + c) * 5 + s]; } break;
    case 4: if (idx < 40960) { int o = idx / 320, r = idx % 320, s = r >> 6, c = r & 63;
            float v = (o < 64) ? (s == 0 ? wal[o * 64 + c] : 0.f)
                               : wat[((o - 64) * 64 + c) * 5 + s];
            wa_[OFF_WHA + idx] = (half_t)v; } break;
    case 5: if (idx < 40960) { int o = idx / 320, r = idx % 320, s = r >> 6, c = r & 63;
            float v = (o < 64) ? (s == 0 ? wbl[o * 64 + c] : 0.f)
                               : wbt[((o - 64) * 64 + c) * 5 + s];
            wa_[OFF_WHB + idx] = (half_t)v; } break;
    case 6: if (idx < 4096)  wa_[OFF_WTA  + idx] = (half_t)wa[idx];  break;
    case 7: if (idx < 4096)  wa_[OFF_WTB  + idx] = (half_t)wb[idx];  break;
    case 8: if (idx < 16384) wa_[OFF_WTAF + idx] = (half_t)waf[idx]; break;
    case 9: if (idx < 16384) wa_[OFF_WTBF + idx] = (half_t)wbf[idx]; break;
    default: {
        int b = blockIdx.y - 10;
        int e = idx;
        if (e < E_TOT) {
            float v[8];
#pragma unroll
            for (int c = 0; c < 8; ++c)
                v[c] = fe[((long)b * 8 + c) * E_TOT + e];
            float4* dst = (float4*)&fet[((long)b * E_TOT + e) * 8];
            dst[0] = make_float4(v[0], v[1], v[2], v[3]);
            dst[1] = make_float4(v[4], v[5], v[6], v[7]);
        }
    } break;
    }
}

// ---------------------------------------------------------------------------
// layer-1 both branches: shared G, K=64, 8 waves (0-3 edge, 4-7 point)
// ---------------------------------------------------------------------------
__global__ __launch_bounds__(512)
void mesh1_both_k(const float* __restrict__ fet, const int* __restrict__ gemm,
                  const half_t* __restrict__ war,
                  const float* __restrict__ be1, const float* __restrict__ bp1,
                  half_t* __restrict__ tmpe, half_t* __restrict__ tmpp,
                  float* __restrict__ parte, float* __restrict__ partp)
{
    __shared__ h8 Gl[64 * 8];
    __shared__ int nidx[64][4];

    const int tid  = threadIdx.x;
    const int b    = blockIdx.y;
    const int e0   = blockIdx.x * TILE_E;
    const int lane = tid & 63;
    const int wv   = tid >> 6;
    const int l15  = lane & 15;
    const int kg   = lane >> 4;
    const int br   = wv >> 2;
    const int o0   = (wv & 3) * 32;

    const float* xb = fet + (long)b * E_TOT * 8;

    if (tid < 256) {
        int e = tid >> 2, s = tid & 3;
        int eg = e0 + e;
        nidx[e][s] = (eg < E_TOT) ? gemm[((long)b * E_TOT + eg) * 4 + s] : 0;
    }
    __syncthreads();

    {
        int e = tid >> 3, g = tid & 7;
        int eg = e0 + e;
        int se = (eg < E_TOT) ? eg : 0;
        h8 r;
        if (g == 0) {
            const float* p = xb + (long)se * 8;
            float4 v0 = *(const float4*)p, v1 = *(const float4*)(p + 4);
            r[0] = (half_t)v0.x; r[1] = (half_t)v0.y; r[2] = (half_t)v0.z; r[3] = (half_t)v0.w;
            r[4] = (half_t)v1.x; r[5] = (half_t)v1.y; r[6] = (half_t)v1.z; r[7] = (half_t)v1.w;
        } else if (g <= 4) {
            int ia = (g == 1 || g == 3) ? 0 : 1;
            const float* pa = xb + (long)nidx[e][ia] * 8;
            const float* pb = xb + (long)nidx[e][ia + 2] * 8;
            float4 a0 = *(const float4*)pa, a1 = *(const float4*)(pa + 4);
            float4 b0 = *(const float4*)pb, b1 = *(const float4*)(pb + 4);
            float aa[8] = {a0.x, a0.y, a0.z, a0.w, a1.x, a1.y, a1.z, a1.w};
            float bb[8] = {b0.x, b0.y, b0.z, b0.w, b1.x, b1.y, b1.z, b1.w};
            if (g <= 2) {
#pragma unroll
                for (int j = 0; j < 8; ++j) r[j] = (half_t)(aa[j] + bb[j]);
            } else {
#pragma unroll
                for (int j = 0; j < 8; ++j) r[j] = (half_t)fabsf(aa[j] - bb[j]);
            }
        } else {
#pragma unroll
            for (int j = 0; j < 8; ++j) r[j] = (half_t)0.f;
        }
        Gl[(e * 8 + g) ^ (e & 7)] = r;
    }
    __syncthreads();

    f32x4 acc[4][2];
#pragma unroll
    for (int mt = 0; mt < 4; ++mt)
#pragma unroll
        for (int nt = 0; nt < 2; ++nt)
#pragma unroll
            for (int j = 0; j < 4; ++j) acc[mt][nt][j] = 0.f;

    const half_t* wt = war + (br ? OFF_W1P : OFF_W1E);
#pragma unroll
    for (int ks = 0; ks < 2; ++ks) {
        h8 bw[2];
#pragma unroll
        for (int nt = 0; nt < 2; ++nt)
            bw[nt] = *(const h8*)(wt + (long)(o0 + nt * 16 + l15) * 64 + ks * 32 + kg * 8);
#pragma unroll
        for (int mt = 0; mt < 4; ++mt) {
            int row = mt * 16 + l15;
            h8 a = Gl[row * 8 + ((ks * 4 + kg) ^ (row & 7))];
#pragma unroll
            for (int nt = 0; nt < 2; ++nt)
                acc[mt][nt] = __builtin_amdgcn_mfma_f32_16x16x32_f16(a, bw[nt], acc[mt][nt], 0, 0, 0);
        }
    }

    const float* bias = br ? bp1 : be1;
    half_t* yb = (br ? tmpp : tmpe) + (long)b * E_TOT * 128;
    float* part = br ? partp : parte;
    float bv[2], s1[2], s2[2];
#pragma unroll
    for (int nt = 0; nt < 2; ++nt) {
        bv[nt] = bias[o0 + nt * 16 + l15];
        s1[nt] = 0.f; s2[nt] = 0.f;
    }
#pragma unroll
    for (int mt = 0; mt < 4; ++mt) {
        int ebase = e0 + mt * 16 + (kg << 2);
#pragma unroll
        for (int j = 0; j < 4; ++j) {
            if (ebase + j < E_TOT) {
#pragma unroll
                for (int nt = 0; nt < 2; ++nt) {
                    float v = acc[mt][nt][j] + bv[nt];
                    yb[(long)(ebase + j) * 128 + o0 + nt * 16 + l15] = (half_t)v;
                    s1[nt] += v; s2[nt] += v * v;
                }
            }
        }
    }
#pragma unroll
    for (int nt = 0; nt < 2; ++nt) {
        s1[nt] += __shfl_xor(s1[nt], 16); s1[nt] += __shfl_xor(s1[nt], 32);
        s2[nt] += __shfl_xor(s2[nt], 16); s2[nt] += __shfl_xor(s2[nt], 32);
    }
    if (lane < 16) {
        long pb = ((long)b * NBLK + blockIdx.x) * 128;
#pragma unroll
        for (int nt = 0; nt < 2; ++nt) {
            part[(pb + o0 + nt * 16 + lane) * 2 + 0] = s1[nt];
            part[(pb + o0 + nt * 16 + lane) * 2 + 1] = s2[nt];
        }
    }
}

// ---------------------------------------------------------------------------
// layer-2 mesh conv — R9-exact: R5-best 5-phase schedule + fused input norm.
// One branch per block (blockIdx.y), 8 waves, 33 KB LDS, 4 blocks/CU.
// ---------------------------------------------------------------------------
__global__ __launch_bounds__(512)
void mesh2_k(const half_t* __restrict__ tmp1e, const half_t* __restrict__ tmp1p,
             const half_t* __restrict__ statshe, const half_t* __restrict__ statshp,
             const int* __restrict__ gemm, const half_t* __restrict__ war,
             const float* __restrict__ be, const float* __restrict__ bp,
             half_t* __restrict__ tmp2e, half_t* __restrict__ tmp2p,
             float* __restrict__ parte, float* __restrict__ partp)
{
    __shared__ h8 GlA[64 * 16];
    __shared__ h8 GlB[64 * 16];
    __shared__ int nidx[64][4];

    const int tid  = threadIdx.x;
    const int br   = blockIdx.y;
    const int b    = blockIdx.z;
    const int e0   = blockIdx.x * TILE_E;
    const int lane = tid & 63;
    const int wv   = tid >> 6;
    const int l15  = lane & 15;
    const int kg   = lane >> 4;
    const int o0   = wv * 16;

    const half_t* xb = (br ? tmp1p : tmp1e) + (long)b * E_TOT * 128;
    const half_t* sh = (br ? statshp : statshe) + (long)b * 256;
    const half_t* wt = war + (br ? OFF_WTP2 : OFF_WTE2);

    const int tc0 = tid & 15;
    const h8 sc8 = *(const h8*)(sh + tc0 * 8);
    const h8 sf8 = *(const h8*)(sh + 128 + tc0 * 8);

    if (tid < 256) {
        int e = tid >> 2, s = tid & 3;
        int eg = e0 + e;
        nidx[e][s] = (eg < E_TOT) ? gemm[((long)b * E_TOT + eg) * 4 + s] : 0;
    }

    auto nrm = [&](h8 v) -> h8 { return hmax0(v * sc8 + sf8); };

    auto stage_self = [&](h8* dst) {
#pragma unroll
        for (int t = 0; t < 2; ++t) {
            int q = t * 512 + tid;
            int e = q >> 4, c8 = q & 15;
            int eg = e0 + e;
            int se = (eg < E_TOT) ? eg : 0;
            dst[(e * 16 + c8) ^ (e & 7)] = nrm(*(const h8*)(xb + (long)se * 128 + c8 * 8));
        }
    };
    auto stage_pair = [&](h8* dstS, h8* dstD, int ia, int ib) {
#pragma unroll
        for (int t = 0; t < 2; ++t) {
            int q = t * 512 + tid;
            int e = q >> 4, c8 = q & 15;
            int na = nidx[e][ia], nb = nidx[e][ib];
            h8 a  = nrm(*(const h8*)(xb + (long)na * 128 + c8 * 8));
            h8 bq = nrm(*(const h8*)(xb + (long)nb * 128 + c8 * 8));
            int slot = (e * 16 + c8) ^ (e & 7);
            dstS[slot] = a + bq;
            dstD[slot] = habs8(a - bq);
        }
    };

    f32x4 acc[4];
#pragma unroll
    for (int mt = 0; mt < 4; ++mt)
#pragma unroll
        for (int j = 0; j < 4; ++j) acc[mt][j] = 0.f;

    auto compute_chunk = [&](const h8* buf, int s) {
#pragma unroll
        for (int ks = 0; ks < 4; ++ks) {
            h8 bw = *(const h8*)(wt + ((long)(o0 + l15) * 5 + s) * 128 + ks * 32 + kg * 8);
#pragma unroll
            for (int mt = 0; mt < 4; ++mt) {
                int row = mt * 16 + l15;
                h8 a = buf[row * 16 + ((ks * 4 + kg) ^ (row & 7))];
                acc[mt] = __builtin_amdgcn_mfma_f32_16x16x32_f16(a, bw, acc[mt], 0, 0, 0);
            }
        }
    };

    stage_self(GlA);
    __syncthreads();
    compute_chunk(GlA, 0);
    __syncthreads();
    stage_pair(GlA, GlB, 0, 2);
    __syncthreads();
    compute_chunk(GlA, 1);
    compute_chunk(GlB, 3);
    __syncthreads();
    stage_pair(GlA, GlB, 1, 3);
    __syncthreads();
    compute_chunk(GlA, 2);
    compute_chunk(GlB, 4);

    const float* bias = br ? bp : be;
    half_t* yb = (br ? tmp2p : tmp2e) + (long)b * E_TOT * 128;
    float* part = br ? partp : parte;
    float bv = bias[o0 + l15];
    float s1 = 0.f, s2 = 0.f;
#pragma unroll
    for (int mt = 0; mt < 4; ++mt) {
        int ebase = e0 + mt * 16 + (kg << 2);
#pragma unroll
        for (int j = 0; j < 4; ++j) {
            if (ebase + j < E_TOT) {
                float v = acc[mt][j] + bv;
                yb[(long)(ebase + j) * 128 + o0 + l15] = (half_t)v;
                s1 += v; s2 += v * v;
            }
        }
    }
    s1 += __shfl_xor(s1, 16); s1 += __shfl_xor(s1, 32);
    s2 += __shfl_xor(s2, 16); s2 += __shfl_xor(s2, 32);
    if (lane < 16) {
        long pb = ((long)b * NBLK + blockIdx.x) * 128;
        part[(pb + o0 + lane) * 2 + 0] = s1;
        part[(pb + o0 + lane) * 2 + 1] = s2;
    }
}

// ---------------------------------------------------------------------------
// FUSED normres + xall (unchanged from R9)
// ---------------------------------------------------------------------------
__global__ __launch_bounds__(512)
void normres_xall_k(const half_t* __restrict__ tmp2e, const half_t* __restrict__ tmp2p,
                    const half_t* __restrict__ tmp1e, const half_t* __restrict__ tmp1p,
                    const half_t* __restrict__ sh1e, const half_t* __restrict__ sh1p,
                    const half_t* __restrict__ sh2e, const half_t* __restrict__ sh2p,
                    const half_t* __restrict__ war,
                    const float* __restrict__ ba, const float* __restrict__ bb,
                    float* __restrict__ outb,
                    half_t* __restrict__ x2e, half_t* __restrict__ x2p,
                    half_t* __restrict__ xall)
{
    __shared__ float Tf[128 * TPAD];
    __shared__ h8 X2t[1024];

    const int tid  = threadIdx.x;
    const int br   = blockIdx.y;
    const int b    = blockIdx.z;
    const int e0   = blockIdx.x * TILE_E;
    const int lane = tid & 63;
    const int wv   = tid >> 6;
    const int l15  = lane & 15;
    const int kg   = lane >> 4;

    const half_t* t2 = (br ? tmp2p : tmp2e) + (long)b * E_TOT * 128;
    const half_t* t1 = (br ? tmp1p : tmp1e) + (long)b * E_TOT * 128;
    const half_t* s1p = (br ? sh1p : sh1e) + (long)b * 256;
    const half_t* s2p = (br ? sh2p : sh2e) + (long)b * 256;
    half_t* x2g = (br ? x2p : x2e) + (long)b * E_TOT * 128;

    const int tc0 = tid & 15;
    const h8 sc1 = *(const h8*)(s1p + tc0 * 8);
    const h8 sf1 = *(const h8*)(s1p + 128 + tc0 * 8);
    const h8 sc2 = *(const h8*)(s2p + tc0 * 8);
    const h8 sf2 = *(const h8*)(s2p + 128 + tc0 * 8);

#pragma unroll
    for (int t = 0; t < 2; ++t) {
        int q = t * 512 + tid;
        int e = q >> 4;
        int eg = e0 + e;
        int se = (eg < E_TOT) ? eg : (E_TOT - 1);
        h8 v2 = *(const h8*)(t2 + (long)se * 128 + tc0 * 8);
        h8 v1 = *(const h8*)(t1 + (long)se * 128 + tc0 * 8);
        h8 x1 = hmax0(v1 * sc1 + sf1);
        h8 x2 = hmax0(v2 * sc2 + sf2 + x1);
        X2t[(e * 16 + tc0) ^ (e & 7)] = x2;
        if (eg < E_TOT) *(h8*)(x2g + (long)eg * 128 + tc0 * 8) = x2;
#pragma unroll
        for (int j = 0; j < 8; ++j)
            Tf[(tc0 * 8 + j) * TPAD + e] = (float)x2[j];
    }
    __syncthreads();

#pragma unroll
    for (int i = 0; i < 4; ++i) {
        int task = i * 512 + tid;
        int cl = task >> 4, eq = task & 15;
        int e4 = e0 + eq * 4;
        float4 v = *(const float4*)&Tf[cl * TPAD + eq * 4];
        int cglob = br * 128 + cl;
        long obase = ((long)b * 384 + cglob) * E_TOT + e4;
        if (e4 + 3 < E_TOT) {
            *(float4*)&outb[obase] = v;
        } else {
            const float* vp = &v.x;
            for (int j = 0; j < 4; ++j)
                if (e4 + j < E_TOT) outb[obase + j] = vp[j];
        }
    }

    const int eoff = (wv & 3) * 16;
    const int og   = wv >> 2;
    const half_t* wt = war + (br ? OFF_WTB : OFF_WTA);
    f32x4 acc;
#pragma unroll
    for (int j = 0; j < 4; ++j) acc[j] = 0.f;
#pragma unroll
    for (int ks = 0; ks < 4; ++ks) {
        h8 bw = *(const h8*)(wt + (long)(og * 16 + l15) * 128 + ks * 32 + kg * 8);
        int row = eoff + l15;
        h8 a = X2t[row * 16 + ((ks * 4 + kg) ^ (row & 7))];
        acc = __builtin_amdgcn_mfma_f32_16x16x32_f16(a, bw, acc, 0, 0, 0);
    }
    float bv = (br ? bb : ba)[og * 16 + l15];
    half_t* yall = xall + (long)b * E_TOT * 64;
#pragma unroll
    for (int j = 0; j < 4; ++j) {
        int e = e0 + eoff + (kg << 2) + j;
        if (e < E_TOT)
            yall[(long)e * 64 + br * 32 + og * 16 + l15] = (half_t)(acc[j] + bv);
    }
}

// ---------------------------------------------------------------------------
// FUSED decoder heads + gates (unchanged from R9)
// ---------------------------------------------------------------------------
__global__ __launch_bounds__(512)
void heads_gates_k(const half_t* __restrict__ xall, const int* __restrict__ gemm,
                   const half_t* __restrict__ war,
                   const float* __restrict__ bal, const float* __restrict__ bbl,
                   const float* __restrict__ bat, const float* __restrict__ bbt,
                   const float* __restrict__ baf, const float* __restrict__ bbf,
                   half_t* __restrict__ gA, half_t* __restrict__ gB,
                   float* __restrict__ parte, float* __restrict__ partp)
{
    __shared__ h8 arena[2048];
    __shared__ int nidx[64][4];

    const int tid  = threadIdx.x;
    const int b    = blockIdx.y;
    const int e0   = blockIdx.x * TILE_E;
    const int lane = tid & 63;
    const int wv   = tid >> 6;
    const int hd   = wv >> 2;
    const int o0   = (wv & 3) * 32;
    const int l15  = lane & 15;
    const int kg   = lane >> 4;

    h8* C0 = arena;
    h8* C1 = arena + 512;
    h8* C2 = arena + 1024;

    const half_t* xb = xall + (long)b * E_TOT * 64;

    if (tid < 256) {
        int e = tid >> 2, s = tid & 3;
        int eg = e0 + e;
        nidx[e][s] = (eg < E_TOT) ? gemm[((long)b * E_TOT + eg) * 4 + s] : 0;
    }
    __syncthreads();

    const int te = tid >> 3, tc = tid & 7;
    const int tslot = (te * 8 + tc) ^ (te & 7);

    {
        int eg = e0 + te;
        int se = (eg < E_TOT) ? eg : 0;
        C0[tslot] = *(const h8*)(xb + (long)se * 64 + tc * 8);
    }
    h8 rA, rB;
    {
        rA = *(const h8*)(xb + (long)nidx[te][0] * 64 + tc * 8);
        rB = *(const h8*)(xb + (long)nidx[te][2] * 64 + tc * 8);
    }
    __syncthreads();

    f32x4 acc[4][2];
#pragma unroll
    for (int mt = 0; mt < 4; ++mt)
#pragma unroll
        for (int nt = 0; nt < 2; ++nt)
#pragma unroll
            for (int j = 0; j < 4; ++j) acc[mt][nt][j] = 0.f;

    const half_t* wt = war + (hd ? OFF_WHB : OFF_WHA);
    auto chunk = [&](const h8* buf, int s) {
#pragma unroll
        for (int ks = 0; ks < 2; ++ks) {
            h8 bw0 = *(const h8*)(wt + ((long)(o0 + l15) * 5 + s) * 64 + ks * 32 + kg * 8);
            h8 bw1 = *(const h8*)(wt + ((long)(o0 + 16 + l15) * 5 + s) * 64 + ks * 32 + kg * 8);
#pragma unroll
            for (int mt = 0; mt < 4; ++mt) {
                int row = mt * 16 + l15;
                h8 a = buf[row * 8 + ((ks * 4 + kg) ^ (row & 7))];
                acc[mt][0] = __builtin_amdgcn_mfma_f32_16x16x32_f16(a, bw0, acc[mt][0], 0, 0, 0);
                acc[mt][1] = __builtin_amdgcn_mfma_f32_16x16x32_f16(a, bw1, acc[mt][1], 0, 0, 0);
            }
        }
    };

    chunk(C0, 0);
    __syncthreads();
    {
        C1[tslot] = rA + rB;
        C2[tslot] = habs8(rA - rB);
        rA = *(const h8*)(xb + (long)nidx[te][1] * 64 + tc * 8);
        rB = *(const h8*)(xb + (long)nidx[te][3] * 64 + tc * 8);
    }
    __syncthreads();
    chunk(C1, 1);
    chunk(C2, 3);
    __syncthreads();
    {
        C1[tslot] = rA + rB;
        C2[tslot] = habs8(rA - rB);
    }
    __syncthreads();
    chunk(C1, 2);
    chunk(C2, 4);
    __syncthreads();

    {
        half_t* X = (half_t*)(arena + hd * 1024);
        float bv[2];
#pragma unroll
        for (int nt = 0; nt < 2; ++nt) {
            int o = o0 + nt * 16 + l15;
            bv[nt] = (o < 64) ? (hd ? bbl[o] : bal[o]) : (hd ? bbt[o - 64] : bat[o - 64]);
        }
#pragma unroll
        for (int mt = 0; mt < 4; ++mt) {
#pragma unroll
            for (int j = 0; j < 4; ++j) {
                int e = mt * 16 + (kg << 2) + j;
#pragma unroll
                for (int nt = 0; nt < 2; ++nt) {
                    int c = o0 + nt * 16 + l15;
                    int slot = (e * 16 + (c >> 3)) ^ (e & 7);
                    X[slot * 8 + (c & 7)] = (half_t)(acc[mt][nt][j] + bv[nt]);
                }
            }
        }
    }
    __syncthreads();

    f32x4 g[4][2];
#pragma unroll
    for (int mt = 0; mt < 4; ++mt)
#pragma unroll
        for (int nt = 0; nt < 2; ++nt)
#pragma unroll
            for (int j = 0; j < 4; ++j) g[mt][nt][j] = 0.f;

    const half_t* wtg = war + (hd ? OFF_WTBF : OFF_WTAF);
    const h8* X = arena + hd * 1024;
#pragma unroll
    for (int ks = 0; ks < 4; ++ks) {
        h8 bw0 = *(const h8*)(wtg + (long)(o0 + l15) * 128 + ks * 32 + kg * 8);
        h8 bw1 = *(const h8*)(wtg + (long)(o0 + 16 + l15) * 128 + ks * 32 + kg * 8);
#pragma unroll
        for (int mt = 0; mt < 4; ++mt) {
            int row = mt * 16 + l15;
            h8 a = X[row * 16 + ((ks * 4 + kg) ^ (row & 7))];
            g[mt][0] = __builtin_amdgcn_mfma_f32_16x16x32_f16(a, bw0, g[mt][0], 0, 0, 0);
            g[mt][1] = __builtin_amdgcn_mfma_f32_16x16x32_f16(a, bw1, g[mt][1], 0, 0, 0);
        }
    }

    const float* biasg = hd ? bbf : baf;
    half_t* yb = (hd ? gB : gA) + (long)b * E_TOT * 128;
    float* part = hd ? partp : parte;
    float bg[2] = {biasg[o0 + l15], biasg[o0 + 16 + l15]};
    float s1[2] = {0.f, 0.f}, s2[2] = {0.f, 0.f};
#pragma unroll
    for (int mt = 0; mt < 4; ++mt) {
        int ebase = e0 + mt * 16 + (kg << 2);
#pragma unroll
        for (int j = 0; j < 4; ++j) {
            if (ebase + j < E_TOT) {
#pragma unroll
                for (int nt = 0; nt < 2; ++nt) {
                    float v = g[mt][nt][j] + bg[nt];
                    yb[(long)(ebase + j) * 128 + o0 + nt * 16 + l15] = (half_t)v;
                    s1[nt] += v; s2[nt] += v * v;
                }
            }
        }
    }
#pragma unroll
    for (int nt = 0; nt < 2; ++nt) {
        s1[nt] += __shfl_xor(s1[nt], 16); s1[nt] += __shfl_xor(s1[nt], 32);
        s2[nt] += __shfl_xor(s2[nt], 16); s2[nt] += __shfl_xor(s2[nt], 32);
    }
    if (lane < 16) {
        long pb = ((long)b * NBLK + blockIdx.x) * 128;
#pragma unroll
        for (int nt = 0; nt < 2; ++nt) {
            part[(pb + o0 + nt * 16 + lane) * 2 + 0] = s1[nt];
            part[(pb + o0 + nt * 16 + lane) * 2 + 1] = s2[nt];
        }
    }
}

// ---------------------------------------------------------------------------
// stats finalize (nblk-parameterized): f32 (mean,rstd) + f16 (scale,shift)
// ---------------------------------------------------------------------------
__global__ __launch_bounds__(256)
void stats2_k(const float* __restrict__ parte, const float* __restrict__ partp,
              int nblk,
              float* __restrict__ statse, float* __restrict__ statsp,
              half_t* __restrict__ statshe, half_t* __restrict__ statshp)
{
    int g = blockIdx.x;
    int br = g >> 8, rem = g & 255, b = rem >> 7, o = rem & 127;
    const float* part = br ? partp : parte;
    float* stats = br ? statsp : statse;
    half_t* statsh = br ? statshp : statshe;
    int tid = threadIdx.x;
    float s1 = 0.f, s2 = 0.f;
    for (int k = tid; k < nblk; k += 256) {
        long base = (((long)b * nblk + k) * 128 + o) * 2;
        s1 += part[base];
        s2 += part[base + 1];
    }
#pragma unroll
    for (int d = 1; d < 64; d <<= 1) {
        s1 += __shfl_xor(s1, d);
        s2 += __shfl_xor(s2, d);
    }
    __shared__ float r1[4], r2[4];
    int wv = tid >> 6;
    if ((tid & 63) == 0) { r1[wv] = s1; r2[wv] = s2; }
    __syncthreads();
    if (tid == 0) {
        s1 = r1[0] + r1[1] + r1[2] + r1[3];
        s2 = r2[0] + r2[1] + r2[2] + r2[3];
        float mean = s1 / (float)E_TOT;
        float var  = s2 / (float)E_TOT - mean * mean;
        var = fmaxf(var, 0.f);
        float rstd = rsqrtf(var + 1e-5f);
        stats[(b * 128 + o) * 2 + 0] = mean;
        stats[(b * 128 + o) * 2 + 1] = rstd;
        statsh[b * 256 + o]       = (half_t)rstd;
        statsh[b * 256 + 128 + o] = (half_t)(-mean * rstd);
    }
}

// ---------------------------------------------------------------------------
// fused gates-norm + softmax2 + aggregate (unchanged)
// ---------------------------------------------------------------------------
__global__ __launch_bounds__(256)
void gate_agg2_k(const half_t* __restrict__ tA, const half_t* __restrict__ tB,
                 const float* __restrict__ statsA, const float* __restrict__ statsB,
                 const half_t* __restrict__ x2e, const half_t* __restrict__ x2p,
                 float* __restrict__ outb)
{
    __shared__ float T[32 * 68];
    int b = blockIdx.z, cg = blockIdx.y;
    int e0 = blockIdx.x * 64;
    int tid = threadIdx.x;
#pragma unroll
    for (int i = 0; i < 2; ++i) {
        int q = tid + i * 256;
        int e = q >> 3, cq = q & 7;
        int eg = e0 + e;
        int se = (eg < E_TOT) ? eg : (E_TOT - 1);
        int c = cg * 32 + cq * 4;
        long base = ((long)b * E_TOT + se) * 128 + c;
        h4 a4 = *(const h4*)&tA[base];
        h4 b4 = *(const h4*)&tB[base];
        h4 xe4 = *(const h4*)&x2e[base];
        h4 xp4 = *(const h4*)&x2p[base];
#pragma unroll
        for (int j = 0; j < 4; ++j) {
            float2 sa = *(const float2*)&statsA[(b * 128 + c + j) * 2];
            float2 sb = *(const float2*)&statsB[(b * 128 + c + j) * 2];
            float na = sigmoidf_(((float)a4[j] - sa.x) * sa.y);
            float nb = sigmoidf_(((float)b4[j] - sb.x) * sb.y);
            float s = sigmoidf_(na - nb);
            T[(cq * 4 + j) * 68 + e] = (float)xe4[j] * s + (float)xp4[j] * (1.f - s);
        }
    }
    __syncthreads();
#pragma unroll
    for (int i = 0; i < 2; ++i) {
        int q = tid + i * 256;
        int cl = q >> 4, eq = q & 15;
        int e4 = e0 + eq * 4;
        int cglob = cg * 32 + cl;
        float4 v = *(const float4*)&T[cl * 68 + eq * 4];
        long ab = ((long)b * 384 + 256 + cglob) * E_TOT + e4;
        if (e4 + 3 < E_TOT) {
            *(float4*)&outb[ab] = v;
        } else {
            const float* vp = &v.x;
            for (int j = 0; j < 4; ++j)
                if (e4 + j < E_TOT) outb[ab + j] = vp[j];
        }
    }
}

// ---------------------------------------------------------------------------
extern "C" void kernel_launch(void* const* d_in, const int* in_sizes, int n_in,
                              void* d_out, int out_size, void* d_ws, size_t ws_size,
                              hipStream_t stream)
{
    const float* fe   = (const float*)d_in[0];
    const int*   gemm = (const int*)  d_in[1];
    const float* w_e1 = (const float*)d_in[2];  const float* b_e1 = (const float*)d_in[3];
    const float* w_p1 = (const float*)d_in[4];  const float* b_p1 = (const float*)d_in[5];
    const float* w_e2 = (const float*)d_in[6];  const float* b_e2 = (const float*)d_in[7];
    const float* w_p2 = (const float*)d_in[8];  const float* b_p2 = (const float*)d_in[9];
    const float* wa   = (const float*)d_in[10]; const float* ba   = (const float*)d_in[11];
    const float* wb   = (const float*)d_in[12]; const float* bb   = (const float*)d_in[13];
    const float* wal  = (const float*)d_in[14]; const float* bal  = (const float*)d_in[15];
    const float* wbl  = (const float*)d_in[16]; const float* bbl  = (const float*)d_in[17];
    const float* wat  = (const float*)d_in[18]; const float* bat  = (const float*)d_in[19];
    const float* wbt  = (const float*)d_in[20]; const float* bbt  = (const float*)d_in[21];
    const float* waf  = (const float*)d_in[22]; const float* baf  = (const float*)d_in[23];
    const float* wbf  = (const float*)d_in[24]; const float* bbf  = (const float*)d_in[25];
    float* out = (float*)d_out;

    const long EB = (long)E_TOT;

    char* wp = (char*)d_ws;
    auto alloc = [&](size_t bytes) -> void* {
        void* r = (void*)wp;
        wp += (bytes + 255) & ~(size_t)255;
        return r;
    };
    float*  FET    = (float*)alloc((size_t)B_TOT * EB * 8 * 4);
    half_t* TMP1_E = (half_t*)alloc((size_t)B_TOT * EB * 128 * 2);
    half_t* TMP1_P = (half_t*)alloc((size_t)B_TOT * EB * 128 * 2);
    half_t* TMP2_E = (half_t*)alloc((size_t)B_TOT * EB * 128 * 2);
    half_t* TMP2_P = (half_t*)alloc((size_t)B_TOT * EB * 128 * 2);
    half_t* X2E    = (half_t*)alloc((size_t)B_TOT * EB * 128 * 2);
    half_t* X2P    = (half_t*)alloc((size_t)B_TOT * EB * 128 * 2);
    half_t* XALL   = (half_t*)alloc((size_t)B_TOT * EB * 64 * 2);
    float*  PART_E = (float*)alloc((size_t)B_TOT * NBLK * 128 * 2 * 4);
    float*  PART_P = (float*)alloc((size_t)B_TOT * NBLK * 128 * 2 * 4);
    float*  STATSE = (float*)alloc((size_t)B_TOT * 128 * 2 * 4);
    float*  STATSP = (float*)alloc((size_t)B_TOT * 128 * 2 * 4);
    half_t* SH1E   = (half_t*)alloc((size_t)B_TOT * 256 * 2);
    half_t* SH1P   = (half_t*)alloc((size_t)B_TOT * 256 * 2);
    half_t* SH2E   = (half_t*)alloc((size_t)B_TOT * 256 * 2);
    half_t* SH2P   = (half_t*)alloc((size_t)B_TOT * 256 * 2);
    half_t* WAR    = (half_t*)alloc((size_t)WARENA_N * 2);

    if ((size_t)(wp - (char*)d_ws) > ws_size) {
        fprintf(stderr, "kernel_launch: ws too small (%zu < %zu)\n",
                ws_size, (size_t)(wp - (char*)d_ws));
        return;
    }

    dim3 blk256(256), blk512(512);
    dim3 gI(NBLK, B_TOT);
    dim3 gE2(NBLK, 2, B_TOT);
    dim3 gM(NBLK, 2, B_TOT);
    dim3 gN4(NBLK, 4, B_TOT);

    // 1: prep (weights + transpose fused)
    wprep_k<<<dim3(320, 12, 1), blk256, 0, stream>>>(WAR, FET, fe,
        w_e1, w_p1, w_e2, w_p2, wat, wbt, wa, wb, wal, wbl, waf, wbf);

    // 2-3: layer 1 (both branches) + stats
    mesh1_both_k<<<gI, blk512, 0, stream>>>(FET, gemm, WAR, b_e1, b_p1,
        TMP1_E, TMP1_P, PART_E, PART_P);
    stats2_k<<<512, blk256, 0, stream>>>(PART_E, PART_P, NBLK, STATSE, STATSP, SH1E, SH1P);

    // 4-5: layer 2 (R9-exact, fused input-norm) + stats
    mesh2_k<<<gM, blk512, 0, stream>>>(TMP1_E, TMP1_P, SH1E, SH1P, gemm, WAR,
        b_e2, b_p2, TMP2_E, TMP2_P, PART_E, PART_P);
    stats2_k<<<512, blk256, 0, stream>>>(PART_E, PART_P, NBLK, STATSE, STATSP, SH2E, SH2P);

    // 6: normres + xall
    normres_xall_k<<<gE2, blk512, 0, stream>>>(TMP2_E, TMP2_P, TMP1_E, TMP1_P,
        SH1E, SH1P, SH2E, SH2P, WAR, ba, bb, out, X2E, X2P, XALL);

    // 7-8: decoder heads + gates (fused) + gate stats
    heads_gates_k<<<gI, blk512, 0, stream>>>(XALL, gemm, WAR,
        bal, bbl, bat, bbt, baf, bbf, TMP1_E, TMP1_P, PART_E, PART_P);
    stats2_k<<<512, blk256, 0, stream>>>(PART_E, PART_P, NBLK, STATSE, STATSP, SH1E, SH1P);

    // 9: aggregate
    gate_agg2_k<<<gN4, blk256, 0, stream>>>(TMP1_E, TMP1_P, STATSE, STATSP,
        X2E, X2P, out);
}